// Round 8
// baseline (412.029 us; speedup 1.0000x reference)
//
#include <hip/hip_runtime.h>
#include <math.h>

#define NB 16
#define TT 800
#define FF 90
#define SS 128
#define LL 200
#define NEGV (-1e30f)

#define NDRX_MAX 32
#define XSTR 68      // X row stride in u32 words (136 bf16: bank-stride 4 -> 2-way only)
#define LN2F 0.69314718055994531f

typedef __attribute__((ext_vector_type(8))) short short8;
typedef __attribute__((ext_vector_type(4))) float float4v;

static __device__ __forceinline__ unsigned short f2bf(float x) {
    union { float f; unsigned u; } v; v.f = x;
    unsigned r = (v.u + 0x7FFFu + ((v.u >> 16) & 1u)) >> 16;
    return (unsigned short)r;
}
// pack two non-negative floats to bf16 pair (round-to-nearest, ties-up)
static __device__ __forceinline__ unsigned pack2bf(float a, float b) {
    const unsigned ua = __float_as_uint(a), ub = __float_as_uint(b);
    return ((ua + 0x8000u) >> 16) | ((ub + 0x8000u) & 0xFFFF0000u);
}

// ======================= Kernel A: node products + numerator =================
// blocks [0, NB*nodes): P_{u,i} = prod_{t=t0}^{t0+ndrx-1} E diag(p_t), bf16,
//   rescaled by pow2; identity for frozen nodes. Transpose-free MFMA chain:
//   X_new^T = E^T * X^T with X row-major in LDS (B-reads and C-writes both
//   row-contiguous -> no shuffles).  Each P matrix = 8192 u32 (128x128 bf16).
// blocks [NB*nodes, +4): numerator chain, one wave per utterance.
__global__ __launch_bounds__(256) void mmi_nodes(
    const float* __restrict__ x,
    const int*   __restrict__ sup,
    const float* __restrict__ trans,
    const int*   __restrict__ den_labels,
    const int*   __restrict__ num_labels,
    const int*   __restrict__ num_lens,
    unsigned*    __restrict__ Pout,     // [NB*nodes][8192] u32 (bf16 pairs)
    float*       __restrict__ scales,   // [NB*nodes] pow2 exponent counts
    float*       __restrict__ nsc,      // [16] numerator scores
    int nodes, int ndrx)
{
    const int tid = threadIdx.x;

    if (blockIdx.x < NB * nodes) {
        __shared__ unsigned Xs[128 * XSTR];        // running product, bf16 pairs
        __shared__ float ptab[NDRX_MAX * SS];      // emission exps
        __shared__ float sh_red[4];

        const int u  = blockIdx.x / nodes;
        const int nd = blockIdx.x - u * nodes;
        const int t0 = nd * ndrx;
        const int nf = sup[u * 3 + 2];
        unsigned* Pg = Pout + (size_t)(u * nodes + nd) * 8192;

        if (t0 >= nf) {   // frozen node -> identity
            #pragma unroll
            for (int k2 = 0; k2 < 32; ++k2) {
                const int ww = tid + k2 * 256;
                const int row = ww >> 6, colw = ww & 63;
                unsigned val = 0;
                if (row == 2 * colw)     val |= 0x3F80u;
                if (row == 2 * colw + 1) val |= 0x3F800000u;
                Pg[ww] = val;
            }
            if (tid == 0) scales[u * nodes + nd] = 0.0f;
            return;
        }

        const int w = tid >> 6, l = tid & 63;
        const int m15 = l & 15, q = l >> 4;
        const int mB = w >> 1;   // column-block of X_new (0..1, 64 cols)
        const int nBk = w & 1;   // row-block of X_new (0..1, 64 rows)

        // A = E^T fragments: afrag[mt][kc][j] = E[kc*32+q*8+j][mB*64+mt*16+m15]
        short8 afrag[4][4];
        #pragma unroll
        for (int mt = 0; mt < 4; ++mt) {
            const int colm = mB * 64 + mt * 16 + m15;
            #pragma unroll
            for (int kc = 0; kc < 4; ++kc) {
                short8 f;
                #pragma unroll
                for (int j = 0; j < 8; ++j)
                    f[j] = (short)f2bf(__expf(trans[(kc * 32 + q * 8 + j) * SS + colm]));
                afrag[mt][kc] = f;
            }
        }

        // emission table: ptab[t][d] = exp(x[u][t0+t][lab[d]])
        for (int idx = tid; idx < ndrx * SS; idx += 256) {
            const int tt = idx >> 7, d = idx & 127;
            ptab[idx] = __expf(x[((size_t)u * TT + (t0 + tt)) * FF + den_labels[d]]);
        }
        __syncthreads();

        // X init = E * diag(p_0), row-major bf16 pairs
        #pragma unroll
        for (int k2 = 0; k2 < 32; ++k2) {
            const int ww = tid + k2 * 256;
            const int row = ww >> 6, colw = ww & 63;
            const float2 t2 = ((const float2*)trans)[ww];
            const float p0 = ptab[2 * colw], p1 = ptab[2 * colw + 1];
            Xs[row * XSTR + colw] = pack2bf(__expf(t2.x) * p0, __expf(t2.y) * p1);
        }
        if (tid < 4) sh_red[tid] = 1.0f;
        int eacc = 0;
        __syncthreads();

        const unsigned short* Xh = (const unsigned short*)Xs;
        const int kmax = min(ndrx, nf - t0);

        for (int k = 1; k < kmax; ++k) {
            // delayed exact pow2 scale from previous step's max
            const float mm = fmaxf(fmaxf(sh_red[0], sh_red[1]),
                                   fmaxf(sh_red[2], sh_red[3]));
            const int e = (int)((__float_as_uint(mm) >> 23) & 255u);
            const float sc = __uint_as_float((unsigned)(254 - e) << 23);
            eacc += (e - 127);

            // C^T = E^T * X^T : B-fragment = contiguous row slice of X
            float4v acc[4][4];
            #pragma unroll
            for (int mt = 0; mt < 4; ++mt)
                #pragma unroll
                for (int nt = 0; nt < 4; ++nt) {
                    float4v z = {0.f, 0.f, 0.f, 0.f};
                    acc[mt][nt] = z;
                }
            #pragma unroll
            for (int kc = 0; kc < 4; ++kc)
                #pragma unroll
                for (int nt = 0; nt < 4; ++nt) {
                    const int row = nBk * 64 + nt * 16 + m15;
                    const short8 bf = *(const short8*)(Xh + row * (2 * XSTR) +
                                                       kc * 32 + q * 8);
                    #pragma unroll
                    for (int mt = 0; mt < 4; ++mt)
                        acc[mt][nt] = __builtin_amdgcn_mfma_f32_16x16x32_bf16(
                            afrag[mt][kc], bf, acc[mt][nt], 0, 0, 0);
                }

            // column scale p_k + pow2 rescale + local max
            float vmax = 0.0f;
            #pragma unroll
            for (int mt = 0; mt < 4; ++mt) {
                const float4 pc = *(const float4*)(ptab + k * SS + mB * 64 +
                                                   mt * 16 + 4 * q);
                #pragma unroll
                for (int nt = 0; nt < 4; ++nt) {
                    acc[mt][nt][0] *= pc.x * sc;
                    acc[mt][nt][1] *= pc.y * sc;
                    acc[mt][nt][2] *= pc.z * sc;
                    acc[mt][nt][3] *= pc.w * sc;
                    vmax = fmaxf(vmax, fmaxf(fmaxf(acc[mt][nt][0], acc[mt][nt][1]),
                                             fmaxf(acc[mt][nt][2], acc[mt][nt][3])));
                }
            }
            #pragma unroll
            for (int off = 32; off >= 1; off >>= 1)
                vmax = fmaxf(vmax, __shfl_xor(vmax, off, 64));

            __syncthreads();   // all X reads retired; prev sh_red consumed
            if (l == 0) sh_red[w] = vmax;

            // write X_new in place: lane holds rows (nBk*64+nt*16+m15),
            // 4 consecutive cols (mB*64+mt*16+4q..+3) -> one uint2, no shuffle
            #pragma unroll
            for (int nt = 0; nt < 4; ++nt) {
                const int row = nBk * 64 + nt * 16 + m15;
                #pragma unroll
                for (int mt = 0; mt < 4; ++mt) {
                    uint2 pk;
                    pk.x = pack2bf(acc[mt][nt][0], acc[mt][nt][1]);
                    pk.y = pack2bf(acc[mt][nt][2], acc[mt][nt][3]);
                    *(uint2*)(Xs + row * XSTR + mB * 32 + mt * 8 + 2 * q) = pk;
                }
            }
            __syncthreads();   // new X + maxes visible
        }

        // write node product (strip padding) + scale
        #pragma unroll
        for (int k2 = 0; k2 < 32; ++k2) {
            const int ww = tid + k2 * 256;
            Pg[ww] = Xs[(ww >> 6) * XSTR + (ww & 63)];
        }
        if (tid == 0) scales[u * nodes + nd] = (float)eacc;
    } else {
        // ---------- numerator: one wave per utterance, barrier-free ----------
        const int w = tid >> 6, l = tid & 63;
        const int n = (blockIdx.x - NB * nodes) * 4 + w;
        const int nf = sup[n * 3 + 2];
        const float* xb = x + (size_t)n * TT * FF;
        const int* nl = num_labels + n * LL;

        int li[4];
        #pragma unroll
        for (int k = 0; k < 4; ++k) li[k] = nl[min(4 * l + k, LL - 1)];

        float a4[4] = {NEGV, NEGV, NEGV, NEGV};
        float ea[4], eb[4];
        #pragma unroll
        for (int k = 0; k < 4; ++k) ea[k] = xb[li[k]];
        {
            const float* xr = xb + (size_t)min(1, nf - 1) * FF;
            #pragma unroll
            for (int k = 0; k < 4; ++k) eb[k] = xr[li[k]];
        }

        auto step = [&](float (&ee)[4], int t) {
            float left = __shfl_up(a4[3], 1, 64);
            if (l == 0) left = (t == 0) ? 0.0f : NEGV;
            float prev = left;
            #pragma unroll
            for (int k = 0; k < 4; ++k) {
                const float a = a4[k], b = prev;
                const float mx = fmaxf(a, b), mn = fminf(a, b);
                const float nv = mx + __logf(1.0f + __expf(mn - mx)) + ee[k];
                prev = a4[k];
                a4[k] = nv;
            }
            const int t2 = min(t + 2, nf - 1);
            const float* xr = xb + (size_t)t2 * FF;
            #pragma unroll
            for (int k = 0; k < 4; ++k) ee[k] = xr[li[k]];
        };

        int t = 0;
        while (t < nf) {
            step(ea, t); ++t;
            if (t >= nf) break;
            step(eb, t); ++t;
        }

        const int idx = num_lens[n] - 1;
        if ((idx >> 2) == l) {
            const int kk = idx & 3;
            float vv = (kk == 0) ? a4[0] : (kk == 1) ? a4[1] : (kk == 2) ? a4[2] : a4[3];
            nsc[n] = vv;
        }
    }
}

// ======================= Kernel B: chain alpha through nodes =================
__global__ __launch_bounds__(256) void mmi_chain(
    const unsigned short* __restrict__ Pmat,   // [16][nodes][128*128] bf16
    const float* __restrict__ scales,          // [16*nodes]
    float* __restrict__ dsc,                   // [16] den scores
    int nodes)
{
    __shared__ float sh_v[SS];
    __shared__ float sh_part[8 * SS];
    __shared__ float sh_red[2];

    const int u = blockIdx.x;
    const int tid = threadIdx.x;
    const int g = tid & 31, c = tid >> 5;
    const unsigned short* Pu = Pmat + (size_t)u * nodes * 16384;

    if (tid < SS) sh_v[tid] = (tid == 0) ? 1.0f : 0.0f;
    int   e2acc = 0;
    float sscal = 0.0f;

    uint2 cur[16], nxt[16];
    #pragma unroll
    for (int j = 0; j < 16; ++j)
        cur[j] = *(const uint2*)(Pu + (16 * c + j) * SS + 4 * g);
    __syncthreads();

    for (int i = 0; i < nodes; ++i) {
        if (i + 1 < nodes) {
            const unsigned short* Pn = Pu + (size_t)(i + 1) * 16384;
            #pragma unroll
            for (int j = 0; j < 16; ++j)
                nxt[j] = *(const uint2*)(Pn + (16 * c + j) * SS + 4 * g);
        }
        sscal += scales[u * nodes + i];

        const float4* av = (const float4*)(sh_v + 16 * c);
        float4 aa[4] = {av[0], av[1], av[2], av[3]};
        const float* as = (const float*)aa;
        float4 acc = make_float4(0.f, 0.f, 0.f, 0.f);
        #pragma unroll
        for (int j = 0; j < 16; ++j) {
            const float e0 = __uint_as_float(cur[j].x << 16);
            const float e1 = __uint_as_float(cur[j].x & 0xFFFF0000u);
            const float e2 = __uint_as_float(cur[j].y << 16);
            const float e3 = __uint_as_float(cur[j].y & 0xFFFF0000u);
            acc.x = fmaf(as[j], e0, acc.x);
            acc.y = fmaf(as[j], e1, acc.y);
            acc.z = fmaf(as[j], e2, acc.z);
            acc.w = fmaf(as[j], e3, acc.w);
        }
        *(float4*)(sh_part + c * SS + 4 * g) = acc;
        __syncthreads();

        float v = 0.0f;
        if (tid < SS) {
            float y = 0.0f;
            #pragma unroll
            for (int cc = 0; cc < 8; ++cc) y += sh_part[cc * SS + tid];
            v = y;
            float m = v;
            #pragma unroll
            for (int off = 32; off >= 1; off >>= 1)
                m = fmaxf(m, __shfl_xor(m, off, 64));
            if ((tid & 63) == 0) sh_red[tid >> 6] = m;
        }
        __syncthreads();
        if (tid < SS) {
            const float mm = fmaxf(fmaxf(sh_red[0], sh_red[1]), 1e-37f);
            const int e = (int)((__float_as_uint(mm) >> 23) & 255u);
            const float inv = __uint_as_float((unsigned)(254 - e) << 23);
            e2acc += (e - 127);
            sh_v[tid] = v * inv;
        }
        #pragma unroll
        for (int j = 0; j < 16; ++j) cur[j] = nxt[j];
        __syncthreads();
    }

    if (tid < SS) {
        float s = sh_v[tid];
        #pragma unroll
        for (int off = 32; off >= 1; off >>= 1)
            s += __shfl_xor(s, off, 64);
        if ((tid & 63) == 0) sh_red[tid >> 6] = s;
    }
    __syncthreads();
    if (tid == 0)
        dsc[u] = LN2F * ((float)e2acc + sscal) + __logf(sh_red[0] + sh_red[1]);
}

// ======================= Finalize ============================================
__global__ void mmi_finalize(const float* __restrict__ sc,
                             const int* __restrict__ sup,
                             float* __restrict__ out)
{
    const int tid = threadIdx.x;
    float tot_score = 0.0f, tot_frames = 0.0f, all_frames = 0.0f;
    if (tid < NB) {
        const float tot = sc[NB + tid] - sc[tid];
        const int nf = sup[tid * 3 + 2];
        const bool fin = isfinite(tot) && (tot > 0.5f * NEGV);
        tot_score  = fin ? tot : 0.0f;
        tot_frames = fin ? (float)nf : 0.0f;
        all_frames = (float)nf;
    }
    #pragma unroll
    for (int off = 32; off >= 1; off >>= 1) {
        tot_score  += __shfl_xor(tot_score, off, 64);
        tot_frames += __shfl_xor(tot_frames, off, 64);
        all_frames += __shfl_xor(all_frames, off, 64);
    }
    if (tid == 0) {
        out[0] = tot_score;
        out[1] = tot_frames;
        out[2] = all_frames;
    }
}

// ======================= Fallback (validated round-4 kernel) =================
#define XBF (16 * FF)
__global__ __launch_bounds__(256) void mmi_forward_fb(
    const float* __restrict__ x, const int* __restrict__ sup,
    const float* __restrict__ trans, const int* __restrict__ den_labels,
    const int* __restrict__ num_labels, const int* __restrict__ num_lens,
    float* __restrict__ ws)
{
    const int tid = threadIdx.x;
    if (blockIdx.x < NB) {
        __shared__ float sh_v[SS];
        __shared__ float sh_part[8 * SS];
        __shared__ float sh_red[4];
        __shared__ __align__(16) float xbuf[2][XBF];
        const int n = blockIdx.x, nf = sup[n * 3 + 2];
        const int g = tid & 31, c = tid >> 5;
        float4 e[16];
        #pragma unroll
        for (int j = 0; j < 16; ++j) {
            const float4 t4 = *(const float4*)(trans + (size_t)(16 * c + j) * SS + 4 * g);
            e[j] = make_float4(__expf(t4.x), __expf(t4.y), __expf(t4.z), __expf(t4.w));
        }
        const int lab = (tid < SS) ? den_labels[tid & (SS - 1)] : 0;
        const float* xb = x + (size_t)n * TT * FF;
        {
            const float4* s0 = (const float4*)xb;
            float4 p0 = s0[tid]; float4 p1; if (tid < 104) p1 = s0[256 + tid];
            float4* d0 = (float4*)xbuf[0];
            d0[tid] = p0; if (tid < 104) d0[256 + tid] = p1;
        }
        if (tid < SS) sh_v[tid] = (tid == 0) ? 1.0f : 0.0f;
        float logM = 0.0f, v = 0.0f, pe = 0.0f;
        float4 pf0, pf1;
        __syncthreads();
        for (int t = 0; t < nf; ++t) {
            const int b = t >> 4;
            if (tid < SS) pe = __expf(xbuf[b & 1][(t & 15) * FF + lab]);
            float4 aa[4];
            { const float4* av = (const float4*)(sh_v + 16 * c);
              aa[0] = av[0]; aa[1] = av[1]; aa[2] = av[2]; aa[3] = av[3]; }
            const float* as = (const float*)aa;
            float4 acc = make_float4(0.f, 0.f, 0.f, 0.f);
            #pragma unroll
            for (int j = 0; j < 16; ++j) {
                acc.x = fmaf(as[j], e[j].x, acc.x); acc.y = fmaf(as[j], e[j].y, acc.y);
                acc.z = fmaf(as[j], e[j].z, acc.z); acc.w = fmaf(as[j], e[j].w, acc.w);
            }
            *(float4*)(sh_part + c * SS + 4 * g) = acc;
            if ((t & 15) == 8) {
                const int tn = (b + 1) * 16;
                if (tn < nf) {
                    const float4* s = (const float4*)(xb + (size_t)tn * FF);
                    pf0 = s[tid]; if (tid < 104) pf1 = s[256 + tid];
                }
            }
            __syncthreads();
            const bool rs = ((t & 15) == 15);
            if (tid < SS) {
                float y = 0.0f;
                #pragma unroll
                for (int cc = 0; cc < 8; ++cc) y += sh_part[cc * SS + tid];
                v = y * pe;
                if (rs) {
                    float m = v;
                    #pragma unroll
                    for (int off = 32; off >= 1; off >>= 1)
                        m = fmaxf(m, __shfl_xor(m, off, 64));
                    if ((tid & 63) == 0) sh_red[tid >> 6] = m;
                }
            }
            if (rs) {
                const int tn = (b + 1) * 16;
                if (tn < nf) {
                    float4* dst = (float4*)xbuf[(b + 1) & 1];
                    dst[tid] = pf0; if (tid < 104) dst[256 + tid] = pf1;
                }
                __syncthreads();
                if (tid < SS) {
                    float mm = fmaxf(fmaxf(sh_red[0], sh_red[1]), 1e-37f);
                    v *= (1.0f / mm); logM += __logf(mm);
                }
            }
            if (tid < SS) sh_v[tid] = v;
            __syncthreads();
        }
        if (tid < SS) {
            float ssum = v;
            #pragma unroll
            for (int off = 32; off >= 1; off >>= 1) ssum += __shfl_xor(ssum, off, 64);
            if ((tid & 63) == 0) sh_red[2 + (tid >> 6)] = ssum;
        }
        __syncthreads();
        if (tid == 0) ws[n] = logM + __logf(sh_red[2] + sh_red[3]);
    } else {
        const int w = tid >> 6, l = tid & 63;
        const int n = (blockIdx.x - NB) * 4 + w;
        const int nf = sup[n * 3 + 2];
        const float* xb = x + (size_t)n * TT * FF;
        const int* nl = num_labels + n * LL;
        int li[4];
        #pragma unroll
        for (int k = 0; k < 4; ++k) li[k] = nl[min(4 * l + k, LL - 1)];
        float a4[4] = {NEGV, NEGV, NEGV, NEGV};
        float ea[4], eb[4];
        #pragma unroll
        for (int k = 0; k < 4; ++k) ea[k] = xb[li[k]];
        { const float* xr = xb + (size_t)min(1, nf - 1) * FF;
          #pragma unroll
          for (int k = 0; k < 4; ++k) eb[k] = xr[li[k]]; }
        auto step = [&](float (&ee)[4], int t) {
            float left = __shfl_up(a4[3], 1, 64);
            if (l == 0) left = (t == 0) ? 0.0f : NEGV;
            float prev = left;
            #pragma unroll
            for (int k = 0; k < 4; ++k) {
                const float a = a4[k], b = prev;
                const float mx = fmaxf(a, b), mn = fminf(a, b);
                const float nv = mx + __logf(1.0f + __expf(mn - mx)) + ee[k];
                prev = a4[k]; a4[k] = nv;
            }
            const int t2 = min(t + 2, nf - 1);
            const float* xr = xb + (size_t)t2 * FF;
            #pragma unroll
            for (int k = 0; k < 4; ++k) ee[k] = xr[li[k]];
        };
        int t = 0;
        while (t < nf) { step(ea, t); ++t; if (t >= nf) break; step(eb, t); ++t; }
        const int idx = num_lens[n] - 1;
        if ((idx >> 2) == l) {
            const int kk = idx & 3;
            float vv = (kk == 0) ? a4[0] : (kk == 1) ? a4[1] : (kk == 2) ? a4[2] : a4[3];
            ws[NB + n] = vv;
        }
    }
}

extern "C" void kernel_launch(void* const* d_in, const int* in_sizes, int n_in,
                              void* d_out, int out_size, void* d_ws, size_t ws_size,
                              hipStream_t stream) {
    const float* x          = (const float*)d_in[0];
    const int*   sup        = (const int*)d_in[1];
    const float* trans      = (const float*)d_in[2];
    const int*   den_labels = (const int*)d_in[3];
    const int*   num_labels = (const int*)d_in[4];
    const int*   num_lens   = (const int*)d_in[5];
    float* out = (float*)d_out;

    const size_t PB50 = (size_t)NB * 50 * 32768 + (NB * 50 + 64) * sizeof(float);
    const size_t PB25 = (size_t)NB * 25 * 32768 + (NB * 25 + 64) * sizeof(float);

    int nodes = 0, ndrx = 0;
    if (ws_size >= PB50)      { nodes = 50; ndrx = 16; }
    else if (ws_size >= PB25) { nodes = 25; ndrx = 32; }

    if (nodes) {
        const size_t PBYTES = (size_t)NB * nodes * 32768;
        unsigned* Pout  = (unsigned*)d_ws;
        float* scales   = (float*)((char*)d_ws + PBYTES);
        float* scores   = scales + NB * nodes;   // [0..15] den, [16..31] num
        mmi_nodes<<<dim3(NB * nodes + 4), dim3(256), 0, stream>>>(
            x, sup, trans, den_labels, num_labels, num_lens,
            Pout, scales, scores + NB, nodes, ndrx);
        mmi_chain<<<dim3(NB), dim3(256), 0, stream>>>(
            (const unsigned short*)d_ws, scales, scores, nodes);
        mmi_finalize<<<dim3(1), dim3(64), 0, stream>>>(scores, sup, out);
    } else {
        float* ws = (float*)d_ws;
        mmi_forward_fb<<<dim3(20), dim3(256), 0, stream>>>(
            x, sup, trans, den_labels, num_labels, num_lens, ws);
        mmi_finalize<<<dim3(1), dim3(64), 0, stream>>>(ws, sup, out);
    }
}

// Round 9
// 334.686 us; speedup vs baseline: 1.2311x; 1.2311x over previous
//
#include <hip/hip_runtime.h>
#include <math.h>

#define NB 16
#define TT 800
#define FF 90
#define SS 128
#define LL 200
#define NEGV (-1e30f)

#define NDRX_MAX 32
#define XSTR 68      // X row stride in u32 words (136 bf16: bank-stride 4 -> 2-way only)
#define LN2F 0.69314718055994531f

typedef __attribute__((ext_vector_type(8))) short short8;
typedef __attribute__((ext_vector_type(4))) float float4v;

static __device__ __forceinline__ unsigned short f2bf(float x) {
    union { float f; unsigned u; } v; v.f = x;
    unsigned r = (v.u + 0x7FFFu + ((v.u >> 16) & 1u)) >> 16;
    return (unsigned short)r;
}
// pack two non-negative floats to bf16 pair (round-to-nearest, ties-up)
static __device__ __forceinline__ unsigned pack2bf(float a, float b) {
    const unsigned ua = __float_as_uint(a), ub = __float_as_uint(b);
    return ((ua + 0x8000u) >> 16) | ((ub + 0x8000u) & 0xFFFF0000u);
}

// ======================= Kernel A ===========================================
// blocks [0, NB): numerator chain, ONE WAVE per utterance, emissions staged
//   through LDS in 32-frame batches (no global latency in the step loop).
// blocks [NB, NB + NB*nodes): P_{u,i} = prod E diag(p_t) via transpose-free
//   MFMA chain (validated round 8).
__global__ __launch_bounds__(256) void mmi_nodes(
    const float* __restrict__ x,
    const int*   __restrict__ sup,
    const float* __restrict__ trans,
    const int*   __restrict__ den_labels,
    const int*   __restrict__ num_labels,
    const int*   __restrict__ num_lens,
    unsigned*    __restrict__ Pout,     // [NB*nodes][8192] u32 (bf16 pairs)
    float*       __restrict__ scales,   // [NB*nodes] pow2 exponent counts
    float*       __restrict__ nsc,      // [16] numerator scores
    int nodes, int ndrx)
{
    __shared__ __align__(16) unsigned Xs[128 * XSTR];   // 34816 B
    __shared__ float ptab[NDRX_MAX * SS];               // 16384 B
    __shared__ float sh_red[4];

    const int tid = threadIdx.x;

    if (blockIdx.x < NB) {
        // ---------- numerator: one wave, LDS-staged emissions ----------
        if (tid >= 64) return;
        const int l = tid;
        const int n = blockIdx.x;
        const int nf = sup[n * 3 + 2];           // in [400, 800]
        const float* xb = x + (size_t)n * TT * FF;
        const int* nl = num_labels + n * LL;
        float* xrow = (float*)Xs;                // [2][32*FF] = 23040 B, aliases Xs

        int li[4];
        #pragma unroll
        for (int k = 0; k < 4; ++k) li[k] = nl[min(4 * l + k, LL - 1)];

        // stage batch 0 (rows 0..31) into buffer 0
        {
            const float4* s0 = (const float4*)xb;
            for (int i = l; i < 720; i += 64) ((float4*)xrow)[i] = s0[i];
        }

        float a4[4] = {NEGV, NEGV, NEGV, NEGV};  // states 4l+1..4l+4
        float ea[4], eb[4];
        #pragma unroll
        for (int k = 0; k < 4; ++k) {            // lgkmcnt wait inserted by compiler
            ea[k] = xrow[0 * FF + li[k]];
            eb[k] = xrow[1 * FF + li[k]];
        }

        auto stepf = [&](float (&ee)[4], int t) {
            float left = __shfl_up(a4[3], 1, 64);
            if (l == 0) left = (t == 0) ? 0.0f : NEGV;
            float prev = left;
            #pragma unroll
            for (int k = 0; k < 4; ++k) {
                const float a = a4[k], b = prev;
                const float mx = fmaxf(a, b), mn = fminf(a, b);
                const float nv = mx + __logf(1.0f + __expf(mn - mx)) + ee[k];
                prev = a4[k];
                a4[k] = nv;
            }
            // refill ee from LDS for step t+2 (always in a committed buffer)
            const int r = t + 2;
            const float* ls = xrow + ((r >> 5) & 1) * 2880 + (r & 31) * FF;
            #pragma unroll
            for (int k = 0; k < 4; ++k) ee[k] = ls[li[k]];
        };

        const int nbat = (nf + 31) >> 5;
        float4 pf[12];
        for (int b = 0; b < nbat; ++b) {
            const bool more = (b + 1 < nbat);
            if (more) {   // issue global prefetch of batch b+1 (~28 steps of slack)
                const float4* s = (const float4*)(xb + (size_t)(b + 1) * 32 * FF);
                #pragma unroll
                for (int i = 0; i < 12; ++i) {
                    const int idx = l + i * 64;
                    if (idx < 720) pf[i] = s[idx];
                }
            }
            const int t0b = b * 32;
            const int nsteps = min(nf - t0b, 32);
            int s = 0, t = t0b;
            while (s < nsteps) {
                if (s == 28 && more) {   // commit batch b+1 into the other buffer
                    float4* d = (float4*)(xrow + ((b + 1) & 1) * 2880);
                    #pragma unroll
                    for (int i = 0; i < 12; ++i) {
                        const int idx = l + i * 64;
                        if (idx < 720) d[idx] = pf[i];
                    }
                }
                stepf(ea, t); ++s; ++t;
                if (s >= nsteps) break;
                stepf(eb, t); ++s; ++t;
            }
        }

        const int idx = num_lens[n] - 1;   // alpha position num_lens = state idx+1
        if ((idx >> 2) == l) {
            const int kk = idx & 3;
            const float vv = (kk == 0) ? a4[0] : (kk == 1) ? a4[1]
                           : (kk == 2) ? a4[2] : a4[3];
            nsc[n] = vv;
        }
        return;
    }

    // ---------------- node products (transpose-free MFMA, round-8) ----------
    {
        const int bid = blockIdx.x - NB;
        const int u  = bid / nodes;
        const int nd = bid - u * nodes;
        const int t0 = nd * ndrx;
        const int nf = sup[u * 3 + 2];
        unsigned* Pg = Pout + (size_t)(u * nodes + nd) * 8192;

        if (t0 >= nf) {   // frozen node -> identity
            #pragma unroll
            for (int k2 = 0; k2 < 32; ++k2) {
                const int ww = tid + k2 * 256;
                const int row = ww >> 6, colw = ww & 63;
                unsigned val = 0;
                if (row == 2 * colw)     val |= 0x3F80u;
                if (row == 2 * colw + 1) val |= 0x3F800000u;
                Pg[ww] = val;
            }
            if (tid == 0) scales[u * nodes + nd] = 0.0f;
            return;
        }

        const int w = tid >> 6, l = tid & 63;
        const int m15 = l & 15, q = l >> 4;
        const int mB = w >> 1;   // column-block of X_new (0..1, 64 cols)
        const int nBk = w & 1;   // row-block of X_new (0..1, 64 rows)

        // A = E^T fragments: afrag[mt][kc][j] = E[kc*32+q*8+j][mB*64+mt*16+m15]
        short8 afrag[4][4];
        #pragma unroll
        for (int mt = 0; mt < 4; ++mt) {
            const int colm = mB * 64 + mt * 16 + m15;
            #pragma unroll
            for (int kc = 0; kc < 4; ++kc) {
                short8 f;
                #pragma unroll
                for (int j = 0; j < 8; ++j)
                    f[j] = (short)f2bf(__expf(trans[(kc * 32 + q * 8 + j) * SS + colm]));
                afrag[mt][kc] = f;
            }
        }

        // emission table: ptab[t][d] = exp(x[u][t0+t][lab[d]])
        for (int idx = tid; idx < ndrx * SS; idx += 256) {
            const int tt = idx >> 7, d = idx & 127;
            ptab[idx] = __expf(x[((size_t)u * TT + (t0 + tt)) * FF + den_labels[d]]);
        }
        __syncthreads();

        // X init = E * diag(p_0), row-major bf16 pairs
        #pragma unroll
        for (int k2 = 0; k2 < 32; ++k2) {
            const int ww = tid + k2 * 256;
            const int row = ww >> 6, colw = ww & 63;
            const float2 t2 = ((const float2*)trans)[ww];
            const float p0 = ptab[2 * colw], p1 = ptab[2 * colw + 1];
            Xs[row * XSTR + colw] = pack2bf(__expf(t2.x) * p0, __expf(t2.y) * p1);
        }
        if (tid < 4) sh_red[tid] = 1.0f;
        int eacc = 0;
        __syncthreads();

        const unsigned short* Xh = (const unsigned short*)Xs;
        const int kmax = min(ndrx, nf - t0);

        for (int k = 1; k < kmax; ++k) {
            // delayed exact pow2 scale from previous step's max
            const float mm = fmaxf(fmaxf(sh_red[0], sh_red[1]),
                                   fmaxf(sh_red[2], sh_red[3]));
            const int e = (int)((__float_as_uint(mm) >> 23) & 255u);
            const float sc = __uint_as_float((unsigned)(254 - e) << 23);
            eacc += (e - 127);

            // C^T = E^T * X^T : B-fragment = contiguous row slice of X
            float4v acc[4][4];
            #pragma unroll
            for (int mt = 0; mt < 4; ++mt)
                #pragma unroll
                for (int nt = 0; nt < 4; ++nt) {
                    float4v z = {0.f, 0.f, 0.f, 0.f};
                    acc[mt][nt] = z;
                }
            #pragma unroll
            for (int kc = 0; kc < 4; ++kc)
                #pragma unroll
                for (int nt = 0; nt < 4; ++nt) {
                    const int row = nBk * 64 + nt * 16 + m15;
                    const short8 bf = *(const short8*)(Xh + row * (2 * XSTR) +
                                                       kc * 32 + q * 8);
                    #pragma unroll
                    for (int mt = 0; mt < 4; ++mt)
                        acc[mt][nt] = __builtin_amdgcn_mfma_f32_16x16x32_bf16(
                            afrag[mt][kc], bf, acc[mt][nt], 0, 0, 0);
                }

            // column scale p_k + pow2 rescale + local max
            float vmax = 0.0f;
            #pragma unroll
            for (int mt = 0; mt < 4; ++mt) {
                const float4 pc = *(const float4*)(ptab + k * SS + mB * 64 +
                                                   mt * 16 + 4 * q);
                #pragma unroll
                for (int nt = 0; nt < 4; ++nt) {
                    acc[mt][nt][0] *= pc.x * sc;
                    acc[mt][nt][1] *= pc.y * sc;
                    acc[mt][nt][2] *= pc.z * sc;
                    acc[mt][nt][3] *= pc.w * sc;
                    vmax = fmaxf(vmax, fmaxf(fmaxf(acc[mt][nt][0], acc[mt][nt][1]),
                                             fmaxf(acc[mt][nt][2], acc[mt][nt][3])));
                }
            }
            #pragma unroll
            for (int off = 32; off >= 1; off >>= 1)
                vmax = fmaxf(vmax, __shfl_xor(vmax, off, 64));

            __syncthreads();   // all X reads retired; prev sh_red consumed
            if (l == 0) sh_red[w] = vmax;

            // write X_new in place: row-contiguous uint2, no shuffle
            #pragma unroll
            for (int nt = 0; nt < 4; ++nt) {
                const int row = nBk * 64 + nt * 16 + m15;
                #pragma unroll
                for (int mt = 0; mt < 4; ++mt) {
                    uint2 pk;
                    pk.x = pack2bf(acc[mt][nt][0], acc[mt][nt][1]);
                    pk.y = pack2bf(acc[mt][nt][2], acc[mt][nt][3]);
                    *(uint2*)(Xs + row * XSTR + mB * 32 + mt * 8 + 2 * q) = pk;
                }
            }
            __syncthreads();   // new X + maxes visible
        }

        // write node product (strip padding) + scale
        #pragma unroll
        for (int k2 = 0; k2 < 32; ++k2) {
            const int ww = tid + k2 * 256;
            Pg[ww] = Xs[(ww >> 6) * XSTR + (ww & 63)];
        }
        if (tid == 0) scales[u * nodes + nd] = (float)eacc;
    }
}

// ======================= Kernel B: chain alpha through nodes =================
__global__ __launch_bounds__(256) void mmi_chain(
    const unsigned short* __restrict__ Pmat,   // [16][nodes][128*128] bf16
    const float* __restrict__ scales,          // [16*nodes]
    float* __restrict__ dsc,                   // [16] den scores
    int nodes)
{
    __shared__ float sh_v[SS];
    __shared__ float sh_part[8 * SS];
    __shared__ float sh_red[2];

    const int u = blockIdx.x;
    const int tid = threadIdx.x;
    const int g = tid & 31, c = tid >> 5;
    const unsigned short* Pu = Pmat + (size_t)u * nodes * 16384;

    if (tid < SS) sh_v[tid] = (tid == 0) ? 1.0f : 0.0f;
    int   e2acc = 0;
    float sscal = 0.0f;

    uint2 cur[16], nxt[16];
    #pragma unroll
    for (int j = 0; j < 16; ++j)
        cur[j] = *(const uint2*)(Pu + (16 * c + j) * SS + 4 * g);
    __syncthreads();

    for (int i = 0; i < nodes; ++i) {
        if (i + 1 < nodes) {
            const unsigned short* Pn = Pu + (size_t)(i + 1) * 16384;
            #pragma unroll
            for (int j = 0; j < 16; ++j)
                nxt[j] = *(const uint2*)(Pn + (16 * c + j) * SS + 4 * g);
        }
        sscal += scales[u * nodes + i];

        const float4* av = (const float4*)(sh_v + 16 * c);
        float4 aa[4] = {av[0], av[1], av[2], av[3]};
        const float* as = (const float*)aa;
        float4 acc = make_float4(0.f, 0.f, 0.f, 0.f);
        #pragma unroll
        for (int j = 0; j < 16; ++j) {
            const float e0 = __uint_as_float(cur[j].x << 16);
            const float e1 = __uint_as_float(cur[j].x & 0xFFFF0000u);
            const float e2 = __uint_as_float(cur[j].y << 16);
            const float e3 = __uint_as_float(cur[j].y & 0xFFFF0000u);
            acc.x = fmaf(as[j], e0, acc.x);
            acc.y = fmaf(as[j], e1, acc.y);
            acc.z = fmaf(as[j], e2, acc.z);
            acc.w = fmaf(as[j], e3, acc.w);
        }
        *(float4*)(sh_part + c * SS + 4 * g) = acc;
        __syncthreads();

        float v = 0.0f;
        if (tid < SS) {
            float y = 0.0f;
            #pragma unroll
            for (int cc = 0; cc < 8; ++cc) y += sh_part[cc * SS + tid];
            v = y;
            float m = v;
            #pragma unroll
            for (int off = 32; off >= 1; off >>= 1)
                m = fmaxf(m, __shfl_xor(m, off, 64));
            if ((tid & 63) == 0) sh_red[tid >> 6] = m;
        }
        __syncthreads();
        if (tid < SS) {
            const float mm = fmaxf(fmaxf(sh_red[0], sh_red[1]), 1e-37f);
            const int e = (int)((__float_as_uint(mm) >> 23) & 255u);
            const float inv = __uint_as_float((unsigned)(254 - e) << 23);
            e2acc += (e - 127);
            sh_v[tid] = v * inv;
        }
        #pragma unroll
        for (int j = 0; j < 16; ++j) cur[j] = nxt[j];
        __syncthreads();
    }

    if (tid < SS) {
        float s = sh_v[tid];
        #pragma unroll
        for (int off = 32; off >= 1; off >>= 1)
            s += __shfl_xor(s, off, 64);
        if ((tid & 63) == 0) sh_red[tid >> 6] = s;
    }
    __syncthreads();
    if (tid == 0)
        dsc[u] = LN2F * ((float)e2acc + sscal) + __logf(sh_red[0] + sh_red[1]);
}

// ======================= Finalize ============================================
__global__ void mmi_finalize(const float* __restrict__ sc,
                             const int* __restrict__ sup,
                             float* __restrict__ out)
{
    const int tid = threadIdx.x;
    float tot_score = 0.0f, tot_frames = 0.0f, all_frames = 0.0f;
    if (tid < NB) {
        const float tot = sc[NB + tid] - sc[tid];
        const int nf = sup[tid * 3 + 2];
        const bool fin = isfinite(tot) && (tot > 0.5f * NEGV);
        tot_score  = fin ? tot : 0.0f;
        tot_frames = fin ? (float)nf : 0.0f;
        all_frames = (float)nf;
    }
    #pragma unroll
    for (int off = 32; off >= 1; off >>= 1) {
        tot_score  += __shfl_xor(tot_score, off, 64);
        tot_frames += __shfl_xor(tot_frames, off, 64);
        all_frames += __shfl_xor(all_frames, off, 64);
    }
    if (tid == 0) {
        out[0] = tot_score;
        out[1] = tot_frames;
        out[2] = all_frames;
    }
}

// ======================= Fallback (validated round-4 kernel) =================
#define XBF (16 * FF)
__global__ __launch_bounds__(256) void mmi_forward_fb(
    const float* __restrict__ x, const int* __restrict__ sup,
    const float* __restrict__ trans, const int* __restrict__ den_labels,
    const int* __restrict__ num_labels, const int* __restrict__ num_lens,
    float* __restrict__ ws)
{
    const int tid = threadIdx.x;
    if (blockIdx.x < NB) {
        __shared__ float sh_v[SS];
        __shared__ float sh_part[8 * SS];
        __shared__ float sh_red[4];
        __shared__ __align__(16) float xbuf[2][XBF];
        const int n = blockIdx.x, nf = sup[n * 3 + 2];
        const int g = tid & 31, c = tid >> 5;
        float4 e[16];
        #pragma unroll
        for (int j = 0; j < 16; ++j) {
            const float4 t4 = *(const float4*)(trans + (size_t)(16 * c + j) * SS + 4 * g);
            e[j] = make_float4(__expf(t4.x), __expf(t4.y), __expf(t4.z), __expf(t4.w));
        }
        const int lab = (tid < SS) ? den_labels[tid & (SS - 1)] : 0;
        const float* xb = x + (size_t)n * TT * FF;
        {
            const float4* s0 = (const float4*)xb;
            float4 p0 = s0[tid]; float4 p1; if (tid < 104) p1 = s0[256 + tid];
            float4* d0 = (float4*)xbuf[0];
            d0[tid] = p0; if (tid < 104) d0[256 + tid] = p1;
        }
        if (tid < SS) sh_v[tid] = (tid == 0) ? 1.0f : 0.0f;
        float logM = 0.0f, v = 0.0f, pe = 0.0f;
        float4 pf0, pf1;
        __syncthreads();
        for (int t = 0; t < nf; ++t) {
            const int b = t >> 4;
            if (tid < SS) pe = __expf(xbuf[b & 1][(t & 15) * FF + lab]);
            float4 aa[4];
            { const float4* av = (const float4*)(sh_v + 16 * c);
              aa[0] = av[0]; aa[1] = av[1]; aa[2] = av[2]; aa[3] = av[3]; }
            const float* as = (const float*)aa;
            float4 acc = make_float4(0.f, 0.f, 0.f, 0.f);
            #pragma unroll
            for (int j = 0; j < 16; ++j) {
                acc.x = fmaf(as[j], e[j].x, acc.x); acc.y = fmaf(as[j], e[j].y, acc.y);
                acc.z = fmaf(as[j], e[j].z, acc.z); acc.w = fmaf(as[j], e[j].w, acc.w);
            }
            *(float4*)(sh_part + c * SS + 4 * g) = acc;
            if ((t & 15) == 8) {
                const int tn = (b + 1) * 16;
                if (tn < nf) {
                    const float4* s = (const float4*)(xb + (size_t)tn * FF);
                    pf0 = s[tid]; if (tid < 104) pf1 = s[256 + tid];
                }
            }
            __syncthreads();
            const bool rs = ((t & 15) == 15);
            if (tid < SS) {
                float y = 0.0f;
                #pragma unroll
                for (int cc = 0; cc < 8; ++cc) y += sh_part[cc * SS + tid];
                v = y * pe;
                if (rs) {
                    float m = v;
                    #pragma unroll
                    for (int off = 32; off >= 1; off >>= 1)
                        m = fmaxf(m, __shfl_xor(m, off, 64));
                    if ((tid & 63) == 0) sh_red[tid >> 6] = m;
                }
            }
            if (rs) {
                const int tn = (b + 1) * 16;
                if (tn < nf) {
                    float4* dst = (float4*)xbuf[(b + 1) & 1];
                    dst[tid] = pf0; if (tid < 104) dst[256 + tid] = pf1;
                }
                __syncthreads();
                if (tid < SS) {
                    float mm = fmaxf(fmaxf(sh_red[0], sh_red[1]), 1e-37f);
                    v *= (1.0f / mm); logM += __logf(mm);
                }
            }
            if (tid < SS) sh_v[tid] = v;
            __syncthreads();
        }
        if (tid < SS) {
            float ssum = v;
            #pragma unroll
            for (int off = 32; off >= 1; off >>= 1) ssum += __shfl_xor(ssum, off, 64);
            if ((tid & 63) == 0) sh_red[2 + (tid >> 6)] = ssum;
        }
        __syncthreads();
        if (tid == 0) ws[n] = logM + __logf(sh_red[2] + sh_red[3]);
    } else {
        const int w = tid >> 6, l = tid & 63;
        const int n = (blockIdx.x - NB) * 4 + w;
        const int nf = sup[n * 3 + 2];
        const float* xb = x + (size_t)n * TT * FF;
        const int* nl = num_labels + n * LL;
        int li[4];
        #pragma unroll
        for (int k = 0; k < 4; ++k) li[k] = nl[min(4 * l + k, LL - 1)];
        float a4[4] = {NEGV, NEGV, NEGV, NEGV};
        float ea[4], eb[4];
        #pragma unroll
        for (int k = 0; k < 4; ++k) ea[k] = xb[li[k]];
        { const float* xr = xb + (size_t)min(1, nf - 1) * FF;
          #pragma unroll
          for (int k = 0; k < 4; ++k) eb[k] = xr[li[k]]; }
        auto step = [&](float (&ee)[4], int t) {
            float left = __shfl_up(a4[3], 1, 64);
            if (l == 0) left = (t == 0) ? 0.0f : NEGV;
            float prev = left;
            #pragma unroll
            for (int k = 0; k < 4; ++k) {
                const float a = a4[k], b = prev;
                const float mx = fmaxf(a, b), mn = fminf(a, b);
                const float nv = mx + __logf(1.0f + __expf(mn - mx)) + ee[k];
                prev = a4[k]; a4[k] = nv;
            }
            const int t2 = min(t + 2, nf - 1);
            const float* xr = xb + (size_t)t2 * FF;
            #pragma unroll
            for (int k = 0; k < 4; ++k) ee[k] = xr[li[k]];
        };
        int t = 0;
        while (t < nf) { step(ea, t); ++t; if (t >= nf) break; step(eb, t); ++t; }
        const int idx = num_lens[n] - 1;
        if ((idx >> 2) == l) {
            const int kk = idx & 3;
            float vv = (kk == 0) ? a4[0] : (kk == 1) ? a4[1] : (kk == 2) ? a4[2] : a4[3];
            ws[NB + n] = vv;
        }
    }
}

extern "C" void kernel_launch(void* const* d_in, const int* in_sizes, int n_in,
                              void* d_out, int out_size, void* d_ws, size_t ws_size,
                              hipStream_t stream) {
    const float* x          = (const float*)d_in[0];
    const int*   sup        = (const int*)d_in[1];
    const float* trans      = (const float*)d_in[2];
    const int*   den_labels = (const int*)d_in[3];
    const int*   num_labels = (const int*)d_in[4];
    const int*   num_lens   = (const int*)d_in[5];
    float* out = (float*)d_out;

    const int nodes = 25, ndrx = 32;
    const size_t PBYTES = (size_t)NB * nodes * 32768;   // 13.1 MB
    const size_t NEEDED = PBYTES + (NB * nodes + 64) * sizeof(float);

    if (ws_size >= NEEDED) {
        unsigned* Pout  = (unsigned*)d_ws;
        float* scales   = (float*)((char*)d_ws + PBYTES);
        float* scores   = scales + NB * nodes;   // [0..15] den, [16..31] num
        mmi_nodes<<<dim3(NB + NB * nodes), dim3(256), 0, stream>>>(
            x, sup, trans, den_labels, num_labels, num_lens,
            Pout, scales, scores + NB, nodes, ndrx);
        mmi_chain<<<dim3(NB), dim3(256), 0, stream>>>(
            (const unsigned short*)d_ws, scales, scores, nodes);
        mmi_finalize<<<dim3(1), dim3(64), 0, stream>>>(scores, sup, out);
    } else {
        float* ws = (float*)d_ws;
        mmi_forward_fb<<<dim3(20), dim3(256), 0, stream>>>(
            x, sup, trans, den_labels, num_labels, num_lens, ws);
        mmi_finalize<<<dim3(1), dim3(64), 0, stream>>>(ws, sup, out);
    }
}

// Round 10
// 224.638 us; speedup vs baseline: 1.8342x; 1.4899x over previous
//
#include <hip/hip_runtime.h>
#include <math.h>

#define NB 16
#define TT 800
#define FF 90
#define SS 128
#define LL 200
#define NEGV (-1e30f)

#define NDRX_MAX 32
#define XSTR 68      // X row stride in u32 words (136 bf16: bank-stride 4 -> 2-way only)
#define LN2F 0.69314718055994531f
#define LOG2E 1.4426950408889634f

typedef __attribute__((ext_vector_type(8))) short short8;
typedef __attribute__((ext_vector_type(4))) float float4v;

static __device__ __forceinline__ unsigned short f2bf(float x) {
    union { float f; unsigned u; } v; v.f = x;
    unsigned r = (v.u + 0x7FFFu + ((v.u >> 16) & 1u)) >> 16;
    return (unsigned short)r;
}
// pack two non-negative floats to bf16 pair (round-to-nearest, ties-up)
static __device__ __forceinline__ unsigned pack2bf(float a, float b) {
    const unsigned ua = __float_as_uint(a), ub = __float_as_uint(b);
    return ((ua + 0x8000u) >> 16) | ((ub + 0x8000u) & 0xFFFF0000u);
}

// ======================= Kernel A ===========================================
// blocks [0, NB): numerator chain. Wave 0 computes (log2 domain, one
//   conflict-free b128 emission read/step); waves 1-3 pre-gather emissions
//   into a dense LDS tile [2][32][200]. One barrier per 32 steps.
// blocks [NB, NB + NB*nodes): node products P = prod E diag(p_t), transpose-
//   free MFMA chain (validated rounds 8/9).
__global__ __launch_bounds__(256) void mmi_nodes(
    const float* __restrict__ x,
    const int*   __restrict__ sup,
    const float* __restrict__ trans,
    const int*   __restrict__ den_labels,
    const int*   __restrict__ num_labels,
    const int*   __restrict__ num_lens,
    unsigned*    __restrict__ Pout,     // [NB*nodes][8192] u32 (bf16 pairs)
    float*       __restrict__ scales,   // [NB*nodes] pow2 exponent counts
    float*       __restrict__ nsc,      // [16] numerator scores
    int nodes, int ndrx)
{
    __shared__ __align__(16) unsigned char SMEM[51232];
    const int tid = threadIdx.x;

    if (blockIdx.x < NB) {
        // ---------------- numerator ----------------
        float* tile = (float*)SMEM;            // [2][32][200] floats = 51200 B
        const int n  = blockIdx.x;
        const int nf = sup[n * 3 + 2];         // in [400, 800]
        const int nbat = (nf + 31) >> 5;
        const float* xb = x + (size_t)n * TT * FF;
        const int* nl = num_labels + n * LL;
        const int w = tid >> 6, l = tid & 63;

        if (w == 0) {
            // ---- compute wave ----
            float a4[4] = {NEGV, NEGV, NEGV, NEGV};   // states 4l+1..4l+4, log2 units
            if (l == 0) { /* alpha[0]=0 handled via l0v */ }
            float l0v = 0.0f;       // left-input for lane 0 (alpha[0]); NEGV after t=0
            const int nfm1 = nf - 1;
            float ee[4];

            __syncthreads();        // batch 0 gathered
            {
                const float4 f4 = *(const float4*)(tile + 4 * l);   // row 0
                ee[0] = f4.x; ee[1] = f4.y; ee[2] = f4.z; ee[3] = f4.w;
            }

            int t = 0;
            auto stepf = [&]() {
                float left = __shfl_up(a4[3], 1, 64);
                if (l == 0) left = l0v;
                l0v = NEGV;
                const float e0 = ee[0], e1 = ee[1], e2v = ee[2], e3 = ee[3];
                // refill for t+1 (independent of the alpha chain)
                const int r = min(t + 1, nfm1);
                const float4 f4 = *(const float4*)(tile + ((r >> 5) & 1) * 6400 +
                                                   (r & 31) * 200 + 4 * l);
                ee[0] = f4.x; ee[1] = f4.y; ee[2] = f4.z; ee[3] = f4.w;
                float prev = left;
                {
                    const float a = a4[0], b = prev, mx = fmaxf(a, b);
                    const float d = fminf(a, b) - mx;
                    prev = a;
                    a4[0] = mx + __builtin_amdgcn_logf(1.0f + __builtin_amdgcn_exp2f(d)) + e0;
                }
                {
                    const float a = a4[1], b = prev, mx = fmaxf(a, b);
                    const float d = fminf(a, b) - mx;
                    prev = a;
                    a4[1] = mx + __builtin_amdgcn_logf(1.0f + __builtin_amdgcn_exp2f(d)) + e1;
                }
                {
                    const float a = a4[2], b = prev, mx = fmaxf(a, b);
                    const float d = fminf(a, b) - mx;
                    prev = a;
                    a4[2] = mx + __builtin_amdgcn_logf(1.0f + __builtin_amdgcn_exp2f(d)) + e2v;
                }
                {
                    const float a = a4[3], b = prev, mx = fmaxf(a, b);
                    const float d = fminf(a, b) - mx;
                    a4[3] = mx + __builtin_amdgcn_logf(1.0f + __builtin_amdgcn_exp2f(d)) + e3;
                }
                ++t;
            };

            for (int b = 0; b < nbat; ++b) {
                const int ns = min(nf - b * 32, 32);
                for (int i = 0; i < ns - 1; ++i) stepf();
                __syncthreads();    // next batch's buffer committed
                stepf();            // last step: refill crosses into next buffer
            }

            const int idx = num_lens[n] - 1;   // state idx+1 at position num_lens
            if ((idx >> 2) == l) {
                const int kk = idx & 3;
                const float vv = (kk == 0) ? a4[0] : (kk == 1) ? a4[1]
                               : (kk == 2) ? a4[2] : a4[3];
                nsc[n] = vv * LN2F;
            }
        } else {
            // ---- gatherer waves (1..3): positions gg and 192+gg (gg<8) ----
            const int gg = (tid - 64);              // 0..191
            const bool has1 = (gg < 8);
            const int L0r = nl[gg];
            const int L1r = has1 ? nl[192 + gg] : 0;

            auto gather = [&](int bb) {
                const int buf = bb & 1;
                const float* src = xb + (size_t)bb * 32 * FF;
                #pragma unroll
                for (int h = 0; h < 2; ++h) {
                    float v0[16], v1[16];
                    #pragma unroll
                    for (int r = 0; r < 16; ++r) {
                        const float* row = src + (h * 16 + r) * FF;
                        v0[r] = row[L0r];
                        if (has1) v1[r] = row[L1r];
                    }
                    #pragma unroll
                    for (int r = 0; r < 16; ++r) {
                        float* drow = tile + buf * 6400 + (h * 16 + r) * 200;
                        drow[gg] = v0[r] * LOG2E;
                        if (has1) drow[192 + gg] = v1[r] * LOG2E;
                    }
                }
            };

            gather(0);
            __syncthreads();
            for (int b = 0; b < nbat; ++b) {
                if (b + 1 < nbat) gather(b + 1);
                __syncthreads();
            }
        }
        return;
    }

    // ---------------- node products (transpose-free MFMA, validated) --------
    {
        unsigned* Xs  = (unsigned*)SMEM;                       // 34816 B
        float* ptab   = (float*)(SMEM + 34816);                // 16384 B
        float* sh_red = (float*)(SMEM + 34816 + 16384);        // 16 B

        const int bid = blockIdx.x - NB;
        const int u  = bid / nodes;
        const int nd = bid - u * nodes;
        const int t0 = nd * ndrx;
        const int nf = sup[u * 3 + 2];
        unsigned* Pg = Pout + (size_t)(u * nodes + nd) * 8192;

        if (t0 >= nf) {   // frozen node -> identity
            #pragma unroll
            for (int k2 = 0; k2 < 32; ++k2) {
                const int ww = tid + k2 * 256;
                const int row = ww >> 6, colw = ww & 63;
                unsigned val = 0;
                if (row == 2 * colw)     val |= 0x3F80u;
                if (row == 2 * colw + 1) val |= 0x3F800000u;
                Pg[ww] = val;
            }
            if (tid == 0) scales[u * nodes + nd] = 0.0f;
            return;
        }

        const int w = tid >> 6, l = tid & 63;
        const int m15 = l & 15, q = l >> 4;
        const int mB = w >> 1;   // column-block of X_new (0..1, 64 cols)
        const int nBk = w & 1;   // row-block of X_new (0..1, 64 rows)

        // A = E^T fragments: afrag[mt][kc][j] = E[kc*32+q*8+j][mB*64+mt*16+m15]
        short8 afrag[4][4];
        #pragma unroll
        for (int mt = 0; mt < 4; ++mt) {
            const int colm = mB * 64 + mt * 16 + m15;
            #pragma unroll
            for (int kc = 0; kc < 4; ++kc) {
                short8 f;
                #pragma unroll
                for (int j = 0; j < 8; ++j)
                    f[j] = (short)f2bf(__expf(trans[(kc * 32 + q * 8 + j) * SS + colm]));
                afrag[mt][kc] = f;
            }
        }

        // emission table: ptab[t][d] = exp(x[u][t0+t][lab[d]])
        for (int idx = tid; idx < ndrx * SS; idx += 256) {
            const int tt = idx >> 7, d = idx & 127;
            ptab[idx] = __expf(x[((size_t)u * TT + (t0 + tt)) * FF + den_labels[d]]);
        }
        __syncthreads();

        // X init = E * diag(p_0), row-major bf16 pairs
        #pragma unroll
        for (int k2 = 0; k2 < 32; ++k2) {
            const int ww = tid + k2 * 256;
            const int row = ww >> 6, colw = ww & 63;
            const float2 t2 = ((const float2*)trans)[ww];
            const float p0 = ptab[2 * colw], p1 = ptab[2 * colw + 1];
            Xs[row * XSTR + colw] = pack2bf(__expf(t2.x) * p0, __expf(t2.y) * p1);
        }
        if (tid < 4) sh_red[tid] = 1.0f;
        int eacc = 0;
        __syncthreads();

        const unsigned short* Xh = (const unsigned short*)Xs;
        const int kmax = min(ndrx, nf - t0);

        for (int k = 1; k < kmax; ++k) {
            const float mm = fmaxf(fmaxf(sh_red[0], sh_red[1]),
                                   fmaxf(sh_red[2], sh_red[3]));
            const int e = (int)((__float_as_uint(mm) >> 23) & 255u);
            const float sc = __uint_as_float((unsigned)(254 - e) << 23);
            eacc += (e - 127);

            float4v acc[4][4];
            #pragma unroll
            for (int mt = 0; mt < 4; ++mt)
                #pragma unroll
                for (int nt = 0; nt < 4; ++nt) {
                    float4v z = {0.f, 0.f, 0.f, 0.f};
                    acc[mt][nt] = z;
                }
            #pragma unroll
            for (int kc = 0; kc < 4; ++kc)
                #pragma unroll
                for (int nt = 0; nt < 4; ++nt) {
                    const int row = nBk * 64 + nt * 16 + m15;
                    const short8 bf = *(const short8*)(Xh + row * (2 * XSTR) +
                                                       kc * 32 + q * 8);
                    #pragma unroll
                    for (int mt = 0; mt < 4; ++mt)
                        acc[mt][nt] = __builtin_amdgcn_mfma_f32_16x16x32_bf16(
                            afrag[mt][kc], bf, acc[mt][nt], 0, 0, 0);
                }

            float vmax = 0.0f;
            #pragma unroll
            for (int mt = 0; mt < 4; ++mt) {
                const float4 pc = *(const float4*)(ptab + k * SS + mB * 64 +
                                                   mt * 16 + 4 * q);
                #pragma unroll
                for (int nt = 0; nt < 4; ++nt) {
                    acc[mt][nt][0] *= pc.x * sc;
                    acc[mt][nt][1] *= pc.y * sc;
                    acc[mt][nt][2] *= pc.z * sc;
                    acc[mt][nt][3] *= pc.w * sc;
                    vmax = fmaxf(vmax, fmaxf(fmaxf(acc[mt][nt][0], acc[mt][nt][1]),
                                             fmaxf(acc[mt][nt][2], acc[mt][nt][3])));
                }
            }
            #pragma unroll
            for (int off = 32; off >= 1; off >>= 1)
                vmax = fmaxf(vmax, __shfl_xor(vmax, off, 64));

            __syncthreads();   // all X reads retired; prev sh_red consumed
            if (l == 0) sh_red[w] = vmax;

            #pragma unroll
            for (int nt = 0; nt < 4; ++nt) {
                const int row = nBk * 64 + nt * 16 + m15;
                #pragma unroll
                for (int mt = 0; mt < 4; ++mt) {
                    uint2 pk;
                    pk.x = pack2bf(acc[mt][nt][0], acc[mt][nt][1]);
                    pk.y = pack2bf(acc[mt][nt][2], acc[mt][nt][3]);
                    *(uint2*)(Xs + row * XSTR + mB * 32 + mt * 8 + 2 * q) = pk;
                }
            }
            __syncthreads();   // new X + maxes visible
        }

        #pragma unroll
        for (int k2 = 0; k2 < 32; ++k2) {
            const int ww = tid + k2 * 256;
            Pg[ww] = Xs[(ww >> 6) * XSTR + (ww & 63)];
        }
        if (tid == 0) scales[u * nodes + nd] = (float)eacc;
    }
}

// ======================= Kernel B: chain alpha through nodes =================
__global__ __launch_bounds__(256) void mmi_chain(
    const unsigned short* __restrict__ Pmat,   // [16][nodes][128*128] bf16
    const float* __restrict__ scales,          // [16*nodes]
    float* __restrict__ dsc,                   // [16] den scores
    int nodes)
{
    __shared__ float sh_v[SS];
    __shared__ float sh_part[8 * SS];
    __shared__ float sh_red[2];

    const int u = blockIdx.x;
    const int tid = threadIdx.x;
    const int g = tid & 31, c = tid >> 5;
    const unsigned short* Pu = Pmat + (size_t)u * nodes * 16384;

    if (tid < SS) sh_v[tid] = (tid == 0) ? 1.0f : 0.0f;
    int   e2acc = 0;
    float sscal = 0.0f;

    uint2 cur[16], nxt[16];
    #pragma unroll
    for (int j = 0; j < 16; ++j)
        cur[j] = *(const uint2*)(Pu + (16 * c + j) * SS + 4 * g);
    __syncthreads();

    for (int i = 0; i < nodes; ++i) {
        if (i + 1 < nodes) {
            const unsigned short* Pn = Pu + (size_t)(i + 1) * 16384;
            #pragma unroll
            for (int j = 0; j < 16; ++j)
                nxt[j] = *(const uint2*)(Pn + (16 * c + j) * SS + 4 * g);
        }
        sscal += scales[u * nodes + i];

        const float4* av = (const float4*)(sh_v + 16 * c);
        float4 aa[4] = {av[0], av[1], av[2], av[3]};
        const float* as = (const float*)aa;
        float4 acc = make_float4(0.f, 0.f, 0.f, 0.f);
        #pragma unroll
        for (int j = 0; j < 16; ++j) {
            const float e0 = __uint_as_float(cur[j].x << 16);
            const float e1 = __uint_as_float(cur[j].x & 0xFFFF0000u);
            const float e2 = __uint_as_float(cur[j].y << 16);
            const float e3 = __uint_as_float(cur[j].y & 0xFFFF0000u);
            acc.x = fmaf(as[j], e0, acc.x);
            acc.y = fmaf(as[j], e1, acc.y);
            acc.z = fmaf(as[j], e2, acc.z);
            acc.w = fmaf(as[j], e3, acc.w);
        }
        *(float4*)(sh_part + c * SS + 4 * g) = acc;
        __syncthreads();

        float v = 0.0f;
        if (tid < SS) {
            float y = 0.0f;
            #pragma unroll
            for (int cc = 0; cc < 8; ++cc) y += sh_part[cc * SS + tid];
            v = y;
            float m = v;
            #pragma unroll
            for (int off = 32; off >= 1; off >>= 1)
                m = fmaxf(m, __shfl_xor(m, off, 64));
            if ((tid & 63) == 0) sh_red[tid >> 6] = m;
        }
        __syncthreads();
        if (tid < SS) {
            const float mm = fmaxf(fmaxf(sh_red[0], sh_red[1]), 1e-37f);
            const int e = (int)((__float_as_uint(mm) >> 23) & 255u);
            const float inv = __uint_as_float((unsigned)(254 - e) << 23);
            e2acc += (e - 127);
            sh_v[tid] = v * inv;
        }
        #pragma unroll
        for (int j = 0; j < 16; ++j) cur[j] = nxt[j];
        __syncthreads();
    }

    if (tid < SS) {
        float s = sh_v[tid];
        #pragma unroll
        for (int off = 32; off >= 1; off >>= 1)
            s += __shfl_xor(s, off, 64);
        if ((tid & 63) == 0) sh_red[tid >> 6] = s;
    }
    __syncthreads();
    if (tid == 0)
        dsc[u] = LN2F * ((float)e2acc + sscal) + __logf(sh_red[0] + sh_red[1]);
}

// ======================= Finalize ============================================
__global__ void mmi_finalize(const float* __restrict__ sc,
                             const int* __restrict__ sup,
                             float* __restrict__ out)
{
    const int tid = threadIdx.x;
    float tot_score = 0.0f, tot_frames = 0.0f, all_frames = 0.0f;
    if (tid < NB) {
        const float tot = sc[NB + tid] - sc[tid];
        const int nf = sup[tid * 3 + 2];
        const bool fin = isfinite(tot) && (tot > 0.5f * NEGV);
        tot_score  = fin ? tot : 0.0f;
        tot_frames = fin ? (float)nf : 0.0f;
        all_frames = (float)nf;
    }
    #pragma unroll
    for (int off = 32; off >= 1; off >>= 1) {
        tot_score  += __shfl_xor(tot_score, off, 64);
        tot_frames += __shfl_xor(tot_frames, off, 64);
        all_frames += __shfl_xor(all_frames, off, 64);
    }
    if (tid == 0) {
        out[0] = tot_score;
        out[1] = tot_frames;
        out[2] = all_frames;
    }
}

// ======================= Fallback (validated round-4 kernel) =================
#define XBF (16 * FF)
__global__ __launch_bounds__(256) void mmi_forward_fb(
    const float* __restrict__ x, const int* __restrict__ sup,
    const float* __restrict__ trans, const int* __restrict__ den_labels,
    const int* __restrict__ num_labels, const int* __restrict__ num_lens,
    float* __restrict__ ws)
{
    const int tid = threadIdx.x;
    if (blockIdx.x < NB) {
        __shared__ float sh_v[SS];
        __shared__ float sh_part[8 * SS];
        __shared__ float sh_red[4];
        __shared__ __align__(16) float xbuf[2][XBF];
        const int n = blockIdx.x, nf = sup[n * 3 + 2];
        const int g = tid & 31, c = tid >> 5;
        float4 e[16];
        #pragma unroll
        for (int j = 0; j < 16; ++j) {
            const float4 t4 = *(const float4*)(trans + (size_t)(16 * c + j) * SS + 4 * g);
            e[j] = make_float4(__expf(t4.x), __expf(t4.y), __expf(t4.z), __expf(t4.w));
        }
        const int lab = (tid < SS) ? den_labels[tid & (SS - 1)] : 0;
        const float* xb = x + (size_t)n * TT * FF;
        {
            const float4* s0 = (const float4*)xb;
            float4 p0 = s0[tid]; float4 p1; if (tid < 104) p1 = s0[256 + tid];
            float4* d0 = (float4*)xbuf[0];
            d0[tid] = p0; if (tid < 104) d0[256 + tid] = p1;
        }
        if (tid < SS) sh_v[tid] = (tid == 0) ? 1.0f : 0.0f;
        float logM = 0.0f, v = 0.0f, pe = 0.0f;
        float4 pf0, pf1;
        __syncthreads();
        for (int t = 0; t < nf; ++t) {
            const int b = t >> 4;
            if (tid < SS) pe = __expf(xbuf[b & 1][(t & 15) * FF + lab]);
            float4 aa[4];
            { const float4* av = (const float4*)(sh_v + 16 * c);
              aa[0] = av[0]; aa[1] = av[1]; aa[2] = av[2]; aa[3] = av[3]; }
            const float* as = (const float*)aa;
            float4 acc = make_float4(0.f, 0.f, 0.f, 0.f);
            #pragma unroll
            for (int j = 0; j < 16; ++j) {
                acc.x = fmaf(as[j], e[j].x, acc.x); acc.y = fmaf(as[j], e[j].y, acc.y);
                acc.z = fmaf(as[j], e[j].z, acc.z); acc.w = fmaf(as[j], e[j].w, acc.w);
            }
            *(float4*)(sh_part + c * SS + 4 * g) = acc;
            if ((t & 15) == 8) {
                const int tn = (b + 1) * 16;
                if (tn < nf) {
                    const float4* s = (const float4*)(xb + (size_t)tn * FF);
                    pf0 = s[tid]; if (tid < 104) pf1 = s[256 + tid];
                }
            }
            __syncthreads();
            const bool rs = ((t & 15) == 15);
            if (tid < SS) {
                float y = 0.0f;
                #pragma unroll
                for (int cc = 0; cc < 8; ++cc) y += sh_part[cc * SS + tid];
                v = y * pe;
                if (rs) {
                    float m = v;
                    #pragma unroll
                    for (int off = 32; off >= 1; off >>= 1)
                        m = fmaxf(m, __shfl_xor(m, off, 64));
                    if ((tid & 63) == 0) sh_red[tid >> 6] = m;
                }
            }
            if (rs) {
                const int tn = (b + 1) * 16;
                if (tn < nf) {
                    float4* dst = (float4*)xbuf[(b + 1) & 1];
                    dst[tid] = pf0; if (tid < 104) dst[256 + tid] = pf1;
                }
                __syncthreads();
                if (tid < SS) {
                    float mm = fmaxf(fmaxf(sh_red[0], sh_red[1]), 1e-37f);
                    v *= (1.0f / mm); logM += __logf(mm);
                }
            }
            if (tid < SS) sh_v[tid] = v;
            __syncthreads();
        }
        if (tid < SS) {
            float ssum = v;
            #pragma unroll
            for (int off = 32; off >= 1; off >>= 1) ssum += __shfl_xor(ssum, off, 64);
            if ((tid & 63) == 0) sh_red[2 + (tid >> 6)] = ssum;
        }
        __syncthreads();
        if (tid == 0) ws[n] = logM + __logf(sh_red[2] + sh_red[3]);
    } else {
        const int w = tid >> 6, l = tid & 63;
        const int n = (blockIdx.x - NB) * 4 + w;
        const int nf = sup[n * 3 + 2];
        const float* xb = x + (size_t)n * TT * FF;
        const int* nl = num_labels + n * LL;
        int li[4];
        #pragma unroll
        for (int k = 0; k < 4; ++k) li[k] = nl[min(4 * l + k, LL - 1)];
        float a4[4] = {NEGV, NEGV, NEGV, NEGV};
        float ea[4], eb[4];
        #pragma unroll
        for (int k = 0; k < 4; ++k) ea[k] = xb[li[k]];
        { const float* xr = xb + (size_t)min(1, nf - 1) * FF;
          #pragma unroll
          for (int k = 0; k < 4; ++k) eb[k] = xr[li[k]]; }
        auto step = [&](float (&ee)[4], int t) {
            float left = __shfl_up(a4[3], 1, 64);
            if (l == 0) left = (t == 0) ? 0.0f : NEGV;
            float prev = left;
            #pragma unroll
            for (int k = 0; k < 4; ++k) {
                const float a = a4[k], b = prev;
                const float mx = fmaxf(a, b), mn = fminf(a, b);
                const float nv = mx + __logf(1.0f + __expf(mn - mx)) + ee[k];
                prev = a4[k]; a4[k] = nv;
            }
            const int t2 = min(t + 2, nf - 1);
            const float* xr = xb + (size_t)t2 * FF;
            #pragma unroll
            for (int k = 0; k < 4; ++k) ee[k] = xr[li[k]];
        };
        int t = 0;
        while (t < nf) { step(ea, t); ++t; if (t >= nf) break; step(eb, t); ++t; }
        const int idx = num_lens[n] - 1;
        if ((idx >> 2) == l) {
            const int kk = idx & 3;
            float vv = (kk == 0) ? a4[0] : (kk == 1) ? a4[1] : (kk == 2) ? a4[2] : a4[3];
            ws[NB + n] = vv;
        }
    }
}

extern "C" void kernel_launch(void* const* d_in, const int* in_sizes, int n_in,
                              void* d_out, int out_size, void* d_ws, size_t ws_size,
                              hipStream_t stream) {
    const float* x          = (const float*)d_in[0];
    const int*   sup        = (const int*)d_in[1];
    const float* trans      = (const float*)d_in[2];
    const int*   den_labels = (const int*)d_in[3];
    const int*   num_labels = (const int*)d_in[4];
    const int*   num_lens   = (const int*)d_in[5];
    float* out = (float*)d_out;

    const int nodes = 25, ndrx = 32;
    const size_t PBYTES = (size_t)NB * nodes * 32768;   // 13.1 MB
    const size_t NEEDED = PBYTES + (NB * nodes + 64) * sizeof(float);

    if (ws_size >= NEEDED) {
        unsigned* Pout  = (unsigned*)d_ws;
        float* scales   = (float*)((char*)d_ws + PBYTES);
        float* scores   = scales + NB * nodes;   // [0..15] den, [16..31] num
        mmi_nodes<<<dim3(NB + NB * nodes), dim3(256), 0, stream>>>(
            x, sup, trans, den_labels, num_labels, num_lens,
            Pout, scales, scores + NB, nodes, ndrx);
        mmi_chain<<<dim3(NB), dim3(256), 0, stream>>>(
            (const unsigned short*)d_ws, scales, scores, nodes);
        mmi_finalize<<<dim3(1), dim3(64), 0, stream>>>(scores, sup, out);
    } else {
        float* ws = (float*)d_ws;
        mmi_forward_fb<<<dim3(20), dim3(256), 0, stream>>>(
            x, sup, trans, den_labels, num_labels, num_lens, ws);
        mmi_finalize<<<dim3(1), dim3(64), 0, stream>>>(ws, sup, out);
    }
}